// Round 9
// baseline (468.090 us; speedup 1.0000x reference)
//
#include <hip/hip_runtime.h>
#include <hip/hip_bf16.h>
#include <stdint.h>

// Problem constants
#define B_N 1024
#define S_N 65536
#define D_N 512
#define NS 32                 // s-chunks; grid = 8 batch-blocks x NS = 256 = 1 block/CU
#define SC (S_N / NS)         // 2048 s per block
#define SB 128                // s subtile (P tile = 128 b x 128 s in LDS)
#define NSUB (SC / SB)        // 16
#define PSTRIDE 136           // Ps row stride in shorts (128 + 8 pad = 272B rows)

typedef __attribute__((ext_vector_type(8))) short bf16x8;   // 8 bf16 in 4 VGPRs
typedef __attribute__((ext_vector_type(4))) float f32x4;

// ---- workspace layout (bytes) ----
#define OFF_MBF   ((size_t)0)                                  // M bf16 (s,d)   64 MiB
#define OFF_MT    (OFF_MBF + (size_t)S_N * D_N * 2)            // M^T bf16 (d,s) 64 MiB
#define OFF_XBF   (OFF_MT  + (size_t)D_N * S_N * 2)            // X bf16         1 MiB
#define OFF_RX    (OFF_XBF + (size_t)B_N * D_N * 2)            // 8*log2e*rsqrt(|x|^2)  4 KiB
#define OFF_RM    (OFF_RX  + (size_t)B_N * 4)                  // rsqrt(|m|^2)   256 KiB
#define OFF_LSUM  (OFF_RM  + (size_t)S_N * 4)                  // softmax denom  4 KiB
#define OFF_OPART (OFF_LSUM + (size_t)B_N * 4)                 // PV partials    64 MiB

__device__ __forceinline__ unsigned short f2bf(float f) {
  unsigned u = __builtin_bit_cast(unsigned, f);
  u += 0x7fffu + ((u >> 16) & 1u);          // RNE
  return (unsigned short)(u >> 16);
}

__device__ __forceinline__ void stage16(const unsigned short* g, unsigned short* l) {
  // async global->LDS, 16B/lane; LDS dest is wave-uniform base + lane*16
  __builtin_amdgcn_global_load_lds(
      (const __attribute__((address_space(1))) void*)g,
      (__attribute__((address_space(3))) void*)l, 16, 0, 0);
}

// ---------------- prep X: bf16 convert + rx = 8*log2e*rsqrt(||x||^2) ----------------
__global__ void k_prep_x(const float* __restrict__ X, unsigned short* __restrict__ Xbf,
                         float* __restrict__ rx) {
  const int row = blockIdx.x;
  const int t = threadIdx.x;  // 0..127
  float4 v = ((const float4*)(X + (size_t)row * D_N))[t];
  float ss = v.x*v.x + v.y*v.y + v.z*v.z + v.w*v.w;
  ushort4 o; o.x = f2bf(v.x); o.y = f2bf(v.y); o.z = f2bf(v.z); o.w = f2bf(v.w);
  ((ushort4*)(Xbf + (size_t)row * D_N))[t] = o;
  #pragma unroll
  for (int m = 1; m < 64; m <<= 1) ss += __shfl_xor(ss, m);
  __shared__ float partial[2];
  if ((t & 63) == 0) partial[t >> 6] = ss;
  __syncthreads();
  if (t == 0) rx[row] = 11.541560327111707f * rsqrtf(fmaxf(partial[0] + partial[1], 1e-24f));
}

// ------- prep M (rewritten): one barrier, streaming, bf16 LDS transpose -------
// Step A: 4 threads/row x 128 d each: 512B contiguous f32 reads, ss + f2bf in
// regs, uint4 Mbf writes, bf16 tile -> LDS with 16B-chunk swizzle phys=c^(r&31)
// (write banks: ((c^r)&7)*4 -> 2 lanes/bank, free).
// Step B: 8 iters; thread = (d-row, 16-s group): 16 conflict-free u16 column
// reads (banks ((d>>3)^s)*4+(d&7)/2 -> 2 lanes/bank), 32B contiguous Mt write.
__global__ __launch_bounds__(256) void k_prep_m(
    const float* __restrict__ M, unsigned short* __restrict__ Mbf,
    unsigned short* __restrict__ Mt, float* __restrict__ rm) {
  __shared__ unsigned short ts[64 * 512];   // 64 KiB bf16 tile, swizzled chunks
  const int t = threadIdx.x;                // 0..255
  const int s0 = blockIdx.x * 64;
  const int r = t >> 2;                     // row 0..63
  const int cq = t & 3;                     // 128-d quarter

  const float4* src = (const float4*)(M + (size_t)(s0 + r) * D_N + cq * 128);
  unsigned short* dstM = Mbf + (size_t)(s0 + r) * D_N + cq * 128;
  unsigned short* trow = ts + r * 512;
  const int r31 = r & 31;

  float ss = 0.f;
  #pragma unroll
  for (int c8 = 0; c8 < 16; ++c8) {         // one 16B chunk (8 shorts) per iter
    float4 v0 = src[c8 * 2];
    float4 v1 = src[c8 * 2 + 1];
    ss += v0.x*v0.x + v0.y*v0.y + v0.z*v0.z + v0.w*v0.w;
    ss += v1.x*v1.x + v1.y*v1.y + v1.z*v1.z + v1.w*v1.w;
    union { unsigned short u[8]; uint4 v; } pk;
    pk.u[0] = f2bf(v0.x); pk.u[1] = f2bf(v0.y); pk.u[2] = f2bf(v0.z); pk.u[3] = f2bf(v0.w);
    pk.u[4] = f2bf(v1.x); pk.u[5] = f2bf(v1.y); pk.u[6] = f2bf(v1.z); pk.u[7] = f2bf(v1.w);
    ((uint4*)dstM)[c8] = pk.v;
    const int c = cq * 16 + c8;             // logical chunk 0..63
    *(uint4*)&trow[(c ^ r31) * 8] = pk.v;   // swizzled LDS store (16B aligned)
  }
  // row ||m||^2: reduce across the 4 threads of this row (consecutive lanes)
  ss += __shfl_xor(ss, 1);
  ss += __shfl_xor(ss, 2);
  if (cq == 0) rm[s0 + r] = rsqrtf(fmaxf(ss, 1e-24f));

  __syncthreads();

  // Step B: Mt[d][s0 + sq*16 .. +16] for d = it*64 + (t>>2), sq = t&3
  const int dd0 = t >> 2, sq = t & 3;
  #pragma unroll
  for (int it = 0; it < 8; ++it) {
    const int dd = it * 64 + dd0;
    const int dc = dd >> 3, d7 = dd & 7;    // d chunk & offset within chunk
    union { unsigned short u[16]; uint4 v4[2]; } o;
    #pragma unroll
    for (int k = 0; k < 16; ++k) {
      const int s = sq * 16 + k;
      o.u[k] = ts[s * 512 + ((dc ^ (s & 31)) << 3) + d7];
    }
    uint4* dt = (uint4*)(Mt + (size_t)dd * S_N + s0 + sq * 16);
    dt[0] = o.v4[0]; dt[1] = o.v4[1];
  }
}

// ======== fused QK -> exp -> PV: R2 structure + 3-ring single-barrier pipeline ========
// (byte-identical to R8 -- control for this round's prep_m change)
__global__ __launch_bounds__(512, 2) void k_fused(
    const unsigned short* __restrict__ Xbf, const unsigned short* __restrict__ Mbf,
    const unsigned short* __restrict__ Mt, const float* __restrict__ rx,
    const float* __restrict__ rminv, float* __restrict__ lsum,
    float* __restrict__ Opart) {
  __shared__ unsigned short sbuf[3][16384]; // 3 x 32 KiB ring (QK: A|B, PV: Mt chunk)
  __shared__ unsigned short Ps[128 * PSTRIDE]; // 34 KiB P tile, padded rows

  const int t = threadIdx.x;               // 0..511
  const int w = t >> 6, lane = t & 63, quad = lane >> 4, l15 = lane & 15;
  const int qr = w >> 1, qc = w & 1;       // wave grid 4x2 (s x b for QK; b x d for PV)
  const int x7 = l15 & 7;

  // XCD swizzle: 8 batch-blocks sharing an s-chunk land on one XCD
  const int bid = blockIdx.x;
  const int xcd = bid & 7, slot = bid >> 3;
  const int bblk = slot & 7;
  const int chunk = xcd * 4 + (slot >> 3);
  const int b0 = bblk * 128;
  const int s0 = chunk * SC;

  f32x4 accO[4][2][4];                     // O accumulator (d-chunk, i, j)
  #pragma unroll
  for (int dc = 0; dc < 4; ++dc)
    #pragma unroll
    for (int i = 0; i < 2; ++i)
      #pragma unroll
      for (int j = 0; j < 4; ++j) accO[dc][i][j] = (f32x4){0.f, 0.f, 0.f, 0.f};

  float ls[4] = {0.f, 0.f, 0.f, 0.f};
  float rxj[4];
  #pragma unroll
  for (int j = 0; j < 4; ++j) rxj[j] = rx[b0 + qc * 64 + j * 16 + l15];

  // stager roles (identical to R2)
  const int srow8 = t >> 3;                                 // QK: 64 rows/issue, 8x16B chunks
  const int sch8  = ((t & 7) ^ (srow8 & 7)) * 8;            // source-side inverse swizzle
  const unsigned short* gX0 = Xbf + (size_t)(b0 + srow8) * D_N + sch8;   // + k0
  const unsigned short* gM0 = Mbf + (size_t)srow8 * D_N + sch8;          // + sS*D_N + k0
  const int mrow = t >> 4;                                  // PV: 32 rows/issue, 16x16B chunks
  const int mch  = ((t & 15) ^ (mrow & 7)) * 8;
  const unsigned short* gT0 = Mt + (size_t)mrow * S_N + mch;             // + dc*128*S_N + sS

  #define ISSUE_QK(sS_, k0_, sl_) do {                                       \
    unsigned short* bA_ = &sbuf[(sl_)][0];                                   \
    unsigned short* bB_ = &sbuf[(sl_)][8192];                                \
    const unsigned short* gM_ = gM0 + (size_t)(sS_) * D_N + (k0_);           \
    stage16(gM_,                   bA_ + w * 512);                           \
    stage16(gM_ + (size_t)64*D_N,  bA_ + 4096 + w * 512);                    \
    const unsigned short* gX_ = gX0 + (k0_);                                 \
    stage16(gX_,                   bB_ + w * 512);                           \
    stage16(gX_ + (size_t)64*D_N,  bB_ + 4096 + w * 512);                    \
  } while (0)

  #define ISSUE_PV(sS_, dc_, sl_) do {                                       \
    unsigned short* bT_ = &sbuf[(sl_)][0];                                   \
    const unsigned short* gT_ = gT0 + (size_t)((dc_) * 128) * S_N + (sS_);   \
    stage16(gT_,                   bT_ + w * 512);                           \
    stage16(gT_ + (size_t)32*S_N,  bT_ + 4096 + w * 512);                    \
    stage16(gT_ + (size_t)64*S_N,  bT_ + 8192 + w * 512);                    \
    stage16(gT_ + (size_t)96*S_N,  bT_ + 12288 + w * 512);                   \
  } while (0)

  // prologue: phases 0 and 1 of sub 0 into slots 0, 1
  ISSUE_QK(s0, 0, 0);
  ISSUE_QK(s0, 64, 1);

  for (int sub = 0; sub < NSUB; ++sub) {
    const int sS = s0 + sub * SB;

    // ---------------- QK phases 0..7 (k0 = ph*64, slot ph%3) ----------------
    f32x4 accP[2][4];
    #pragma unroll
    for (int i = 0; i < 2; ++i)
      #pragma unroll
      for (int j = 0; j < 4; ++j) accP[i][j] = (f32x4){0.f, 0.f, 0.f, 0.f};

    #pragma unroll
    for (int ph = 0; ph < 8; ++ph) {
      asm volatile("s_waitcnt vmcnt(4)" ::: "memory");
      __builtin_amdgcn_s_barrier();
      if (ph < 6) { ISSUE_QK(sS, (ph + 2) * 64, (ph + 2) % 3); }
      else        { ISSUE_PV(sS, ph - 6, (ph + 2) % 3); }
      const unsigned short* As = &sbuf[ph % 3][0];
      const unsigned short* Bs = &sbuf[ph % 3][8192];
      __builtin_amdgcn_s_setprio(1);
      #pragma unroll
      for (int kk = 0; kk < 64; kk += 32) {
        const int cq = (kk >> 3) + quad;
        bf16x8 a[2], b[4];
        #pragma unroll
        for (int i = 0; i < 2; ++i)
          a[i] = *(const bf16x8*)&As[(qr * 32 + i * 16 + l15) * 64 + ((cq ^ x7) << 3)];
        #pragma unroll
        for (int j = 0; j < 4; ++j)
          b[j] = *(const bf16x8*)&Bs[(qc * 64 + j * 16 + l15) * 64 + ((cq ^ x7) << 3)];
        #pragma unroll
        for (int i = 0; i < 2; ++i)
          #pragma unroll
          for (int j = 0; j < 4; ++j)
            accP[i][j] = __builtin_amdgcn_mfma_f32_16x16x32_bf16(a[i], b[j], accP[i][j], 0, 0, 0);
      }
      __builtin_amdgcn_s_setprio(0);
    }

    // ------------- epilogue: p = exp2(dot * rx_b * rm_s), rowsum, P -> LDS -------------
    // C layout: s = qr*32 + i*16 + quad*4 + r (4 consecutive), b = qc*64 + j*16 + l15
    {
      const float4 rm0 = *(const float4*)&rminv[sS + qr * 32 + quad * 4];
      const float4 rm1 = *(const float4*)&rminv[sS + qr * 32 + 16 + quad * 4];
      #pragma unroll
      for (int i = 0; i < 2; ++i) {
        const float4 rm = i ? rm1 : rm0;
        const int sl = qr * 32 + i * 16 + quad * 4;   // local s base (mult of 4)
        #pragma unroll
        for (int j = 0; j < 4; ++j) {
          const float p0 = exp2f(accP[i][j][0] * rxj[j] * rm.x);
          const float p1 = exp2f(accP[i][j][1] * rxj[j] * rm.y);
          const float p2 = exp2f(accP[i][j][2] * rxj[j] * rm.z);
          const float p3 = exp2f(accP[i][j][3] * rxj[j] * rm.w);
          ls[j] += (p0 + p1) + (p2 + p3);
          const int brow = qc * 64 + j * 16 + l15;
          uint2 pk;
          pk.x = (unsigned)f2bf(p0) | ((unsigned)f2bf(p1) << 16);
          pk.y = (unsigned)f2bf(p2) | ((unsigned)f2bf(p3) << 16);
          *(uint2*)&Ps[brow * PSTRIDE + sl] = pk;       // padded row, no swizzle needed
        }
      }
      asm volatile("s_waitcnt lgkmcnt(0)" ::: "memory");  // Ps writes done before next barrier
    }

    // ---------------- PV phases 8..11 (dc = 0..3, slot (8+dc)%3) ----------------
    #pragma unroll
    for (int dc = 0; dc < 4; ++dc) {
      if (dc == 3 && sub == NSUB - 1) asm volatile("s_waitcnt vmcnt(0)" ::: "memory");
      else                            asm volatile("s_waitcnt vmcnt(4)" ::: "memory");
      __builtin_amdgcn_s_barrier();
      if (dc < 2)                { ISSUE_PV(sS, dc + 2, (10 + dc) % 3); }
      else if (sub < NSUB - 1)   { ISSUE_QK(sS + SB, (dc - 2) * 64, (10 + dc) % 3); }
      const unsigned short* Tsb = &sbuf[(8 + dc) % 3][0];
      __builtin_amdgcn_s_setprio(1);
      #pragma unroll
      for (int kk = 0; kk < 128; kk += 32) {
        const int cq = (kk >> 3) + quad;
        bf16x8 pa[2], mb[4];
        #pragma unroll
        for (int i = 0; i < 2; ++i)
          pa[i] = *(const bf16x8*)&Ps[(qr * 32 + i * 16 + l15) * PSTRIDE + (cq << 3)];
        #pragma unroll
        for (int j = 0; j < 4; ++j)
          mb[j] = *(const bf16x8*)&Tsb[(qc * 64 + j * 16 + l15) * 128 + ((cq ^ x7) << 3)];
        #pragma unroll
        for (int i = 0; i < 2; ++i)
          #pragma unroll
          for (int j = 0; j < 4; ++j)
            accO[dc][i][j] = __builtin_amdgcn_mfma_f32_16x16x32_bf16(pa[i], mb[j], accO[dc][i][j], 0, 0, 0);
      }
      __builtin_amdgcn_s_setprio(0);
    }
  }

  // ---------------- write O partials (coalesced over d via l15) ----------------
  float* Od = Opart + (size_t)chunk * ((size_t)B_N * D_N);
  #pragma unroll
  for (int dc = 0; dc < 4; ++dc)
    #pragma unroll
    for (int i = 0; i < 2; ++i)
      #pragma unroll
      for (int r = 0; r < 4; ++r) {
        const int bb = b0 + qr * 32 + i * 16 + quad * 4 + r;
        #pragma unroll
        for (int j = 0; j < 4; ++j) {
          const int d = dc * 128 + qc * 64 + j * 16 + l15;
          Od[(size_t)bb * D_N + d] = accO[dc][i][j][r];
        }
      }

  // ---------------- lsum: quad-reduce, cross-wave via LDS, one atomic per b ----------------
  __syncthreads();
  float* red = (float*)&sbuf[0][0];          // 8 waves x 64 b-slots
  #pragma unroll
  for (int j = 0; j < 4; ++j) {
    float v = ls[j];
    v += __shfl_xor(v, 16);
    v += __shfl_xor(v, 32);
    if (lane < 16) red[w * 64 + j * 16 + lane] = v;
  }
  __syncthreads();
  if (t < 128) {
    const int qc2 = t >> 6, idx = t & 63;
    float s = red[(0 + qc2) * 64 + idx] + red[(2 + qc2) * 64 + idx] +
              red[(4 + qc2) * 64 + idx] + red[(6 + qc2) * 64 + idx];
    unsafeAtomicAdd(&lsum[b0 + t], s);
  }
  #undef ISSUE_QK
  #undef ISSUE_PV
}

// ---------------- combine: out = (sum_ks Opart) / lsum ----------------
__global__ void k_combine(const float* __restrict__ Opart, const float* __restrict__ lsum,
                          float* __restrict__ out) {
  const int idx = blockIdx.x * 256 + threadIdx.x;  // float4 index, 131072 total
  const int b = idx >> 7;
  float4 s = {0.f, 0.f, 0.f, 0.f};
  #pragma unroll
  for (int ks = 0; ks < NS; ++ks) {
    float4 v = ((const float4*)Opart)[(size_t)ks * (B_N * D_N / 4) + idx];
    s.x += v.x; s.y += v.y; s.z += v.z; s.w += v.w;
  }
  const float inv = 1.0f / lsum[b];
  s.x *= inv; s.y *= inv; s.z *= inv; s.w *= inv;
  ((float4*)out)[idx] = s;
}

extern "C" void kernel_launch(void* const* d_in, const int* in_sizes, int n_in,
                              void* d_out, int out_size, void* d_ws, size_t ws_size,
                              hipStream_t stream) {
  const float* X = (const float*)d_in[0];
  const float* M = (const float*)d_in[1];
  char* ws = (char*)d_ws;
  unsigned short* Mbf = (unsigned short*)(ws + OFF_MBF);
  unsigned short* Mt  = (unsigned short*)(ws + OFF_MT);
  unsigned short* Xbf = (unsigned short*)(ws + OFF_XBF);
  float* rxv  = (float*)(ws + OFF_RX);
  float* rmv  = (float*)(ws + OFF_RM);
  float* lsum = (float*)(ws + OFF_LSUM);
  float* Opart = (float*)(ws + OFF_OPART);

  hipMemsetAsync(lsum, 0, B_N * sizeof(float), stream);
  k_prep_x<<<dim3(B_N), 128, 0, stream>>>(X, Xbf, rxv);
  k_prep_m<<<dim3(S_N / 64), 256, 0, stream>>>(M, Mbf, Mt, rmv);
  k_fused<<<dim3(8 * NS), 512, 0, stream>>>(Xbf, Mbf, Mt, rxv, rmv, lsum, Opart);
  k_combine<<<dim3(B_N * D_N / 4 / 256), 256, 0, stream>>>(Opart, lsum, (float*)d_out);
}

// Round 10
// 432.382 us; speedup vs baseline: 1.0826x; 1.0826x over previous
//
#include <hip/hip_runtime.h>
#include <hip/hip_bf16.h>
#include <stdint.h>

// Problem constants
#define B_N 1024
#define S_N 65536
#define D_N 512
#define NS 32                 // s-chunks; grid = 8 batch-blocks x NS = 256 = 1 block/CU
#define SC (S_N / NS)         // 2048 s per block
#define SB 128                // s subtile (P tile = 128 b x 128 s in LDS)
#define NSUB (SC / SB)        // 16
#define PSTRIDE 136           // Ps row stride in shorts (128 + 8 pad = 272B rows)

typedef __attribute__((ext_vector_type(8))) short bf16x8;   // 8 bf16 in 4 VGPRs
typedef __attribute__((ext_vector_type(4))) float f32x4;

// ---- workspace layout (bytes) ----
#define OFF_MBF   ((size_t)0)                                  // M bf16 (s,d)   64 MiB
#define OFF_MT    (OFF_MBF + (size_t)S_N * D_N * 2)            // M^T bf16 (d,s) 64 MiB
#define OFF_XBF   (OFF_MT  + (size_t)D_N * S_N * 2)            // X bf16         1 MiB
#define OFF_RX    (OFF_XBF + (size_t)B_N * D_N * 2)            // 8*log2e*rsqrt(|x|^2)  4 KiB
#define OFF_RM    (OFF_RX  + (size_t)B_N * 4)                  // rsqrt(|m|^2)   256 KiB
#define OFF_LSUM  (OFF_RM  + (size_t)S_N * 4)                  // softmax denom  4 KiB
#define OFF_OPART (OFF_LSUM + (size_t)B_N * 4)                 // PV partials    64 MiB

__device__ __forceinline__ unsigned short f2bf(float f) {
  unsigned u = __builtin_bit_cast(unsigned, f);
  u += 0x7fffu + ((u >> 16) & 1u);          // RNE
  return (unsigned short)(u >> 16);
}

__device__ __forceinline__ void stage16(const unsigned short* g, unsigned short* l) {
  // async global->LDS, 16B/lane; LDS dest is wave-uniform base + lane*16
  __builtin_amdgcn_global_load_lds(
      (const __attribute__((address_space(1))) void*)g,
      (__attribute__((address_space(3))) void*)l, 16, 0, 0);
}

// ---------------- prep X: bf16 convert + rx = 8*log2e*rsqrt(||x||^2) ----------------
__global__ void k_prep_x(const float* __restrict__ X, unsigned short* __restrict__ Xbf,
                         float* __restrict__ rx) {
  const int row = blockIdx.x;
  const int t = threadIdx.x;  // 0..127
  float4 v = ((const float4*)(X + (size_t)row * D_N))[t];
  float ss = v.x*v.x + v.y*v.y + v.z*v.z + v.w*v.w;
  ushort4 o; o.x = f2bf(v.x); o.y = f2bf(v.y); o.z = f2bf(v.z); o.w = f2bf(v.w);
  ((ushort4*)(Xbf + (size_t)row * D_N))[t] = o;
  #pragma unroll
  for (int m = 1; m < 64; m <<= 1) ss += __shfl_xor(ss, m);
  __shared__ float partial[2];
  if ((t & 63) == 0) partial[t >> 6] = ss;
  __syncthreads();
  if (t == 0) rx[row] = 11.541560327111707f * rsqrtf(fmaxf(partial[0] + partial[1], 1e-24f));
}

// ---------------- k_cvt: M f32 -> Mbf bf16 + rm, pure streaming ----------------
// 4096 blocks x 256 thr; 16 lanes/row; 256B-contiguous reads, 128B writes,
// shfl-reduce ||m||^2 within 16 lanes. No LDS, no syncthreads.
__global__ __launch_bounds__(256) void k_cvt(const float* __restrict__ M,
                                             unsigned short* __restrict__ Mbf,
                                             float* __restrict__ rm) {
  const int t = threadIdx.x;
  const int r = t >> 4, li = t & 15;
  const int row = blockIdx.x * 16 + r;
  const float4* src = (const float4*)(M + (size_t)row * D_N);
  ushort4* dst = (ushort4*)(Mbf + (size_t)row * D_N);
  float ss = 0.f;
  #pragma unroll
  for (int i = 0; i < 8; ++i) {
    float4 v = src[li + 16 * i];
    ss += v.x*v.x + v.y*v.y + v.z*v.z + v.w*v.w;
    ushort4 o; o.x = f2bf(v.x); o.y = f2bf(v.y); o.z = f2bf(v.z); o.w = f2bf(v.w);
    dst[li + 16 * i] = o;
  }
  ss += __shfl_xor(ss, 1);
  ss += __shfl_xor(ss, 2);
  ss += __shfl_xor(ss, 4);
  ss += __shfl_xor(ss, 8);
  if (li == 0) rm[row] = rsqrtf(fmaxf(ss, 1e-24f));
}

// ---------------- k_tr: Mbf -> Mt transpose, register 2x2 micro-transpose ----------------
// 2048 blocks, tile 128d x 128s, LDS [128d][64 s-pairs] u32 = 32 KB.
// Phase 1: thread loads 16B from rows 2sp,2sp+1 (same 8-d chunk), packs
// (M[2sp][d], M[2sp+1][d]) into u32, scalar-writes 8 u32 into d-major LDS rows
// (banks sp%32 -> 2 lanes/bank, free). Phase 2: b128 LDS row reads -> 16B
// coalesced Mt writes (16 lanes = 256B/row contiguous). One barrier.
__global__ __launch_bounds__(256) void k_tr(const unsigned short* __restrict__ Mbf,
                                            unsigned short* __restrict__ Mt) {
  __shared__ unsigned int ts[128 * 64];     // [d 128][sp 64] u32, 32 KiB
  const int t = threadIdx.x;
  const int d0 = (int)(blockIdx.x & 3) * 128;
  const int sS = (int)(blockIdx.x >> 2) * 128;
  #pragma unroll
  for (int i = 0; i < 4; ++i) {
    const int pc = t + 256 * i;
    const int sp = pc & 63, dc = pc >> 6;   // s-pair 0..63, d-chunk 0..15
    const unsigned short* pA = Mbf + (size_t)(sS + 2 * sp) * D_N + d0 + dc * 8;
    uint4 a = *(const uint4*)pA;
    uint4 b = *(const uint4*)(pA + D_N);
    const unsigned short* as = (const unsigned short*)&a;
    const unsigned short* bs = (const unsigned short*)&b;
    #pragma unroll
    for (int j = 0; j < 8; ++j)
      ts[(dc * 8 + j) * 64 + sp] = (unsigned)as[j] | ((unsigned)bs[j] << 16);
  }
  __syncthreads();
  #pragma unroll
  for (int i = 0; i < 8; ++i) {
    const int q = t + 256 * i;
    const int spc = q & 15, dr = q >> 4;    // s-chunk 0..15 (8 s), d-row 0..127
    uint4 v = *(const uint4*)&ts[dr * 64 + spc * 4];
    *(uint4*)(Mt + (size_t)(d0 + dr) * S_N + sS + spc * 8) = v;
  }
}

// ======== fused QK -> exp -> PV: R2 structure + 3-ring single-barrier pipeline ========
// (byte-identical to R8 -- control)
__global__ __launch_bounds__(512, 2) void k_fused(
    const unsigned short* __restrict__ Xbf, const unsigned short* __restrict__ Mbf,
    const unsigned short* __restrict__ Mt, const float* __restrict__ rx,
    const float* __restrict__ rminv, float* __restrict__ lsum,
    float* __restrict__ Opart) {
  __shared__ unsigned short sbuf[3][16384]; // 3 x 32 KiB ring (QK: A|B, PV: Mt chunk)
  __shared__ unsigned short Ps[128 * PSTRIDE]; // 34 KiB P tile, padded rows

  const int t = threadIdx.x;               // 0..511
  const int w = t >> 6, lane = t & 63, quad = lane >> 4, l15 = lane & 15;
  const int qr = w >> 1, qc = w & 1;       // wave grid 4x2 (s x b for QK; b x d for PV)
  const int x7 = l15 & 7;

  // XCD swizzle: 8 batch-blocks sharing an s-chunk land on one XCD
  const int bid = blockIdx.x;
  const int xcd = bid & 7, slot = bid >> 3;
  const int bblk = slot & 7;
  const int chunk = xcd * 4 + (slot >> 3);
  const int b0 = bblk * 128;
  const int s0 = chunk * SC;

  f32x4 accO[4][2][4];                     // O accumulator (d-chunk, i, j)
  #pragma unroll
  for (int dc = 0; dc < 4; ++dc)
    #pragma unroll
    for (int i = 0; i < 2; ++i)
      #pragma unroll
      for (int j = 0; j < 4; ++j) accO[dc][i][j] = (f32x4){0.f, 0.f, 0.f, 0.f};

  float ls[4] = {0.f, 0.f, 0.f, 0.f};
  float rxj[4];
  #pragma unroll
  for (int j = 0; j < 4; ++j) rxj[j] = rx[b0 + qc * 64 + j * 16 + l15];

  // stager roles (identical to R2)
  const int srow8 = t >> 3;                                 // QK: 64 rows/issue, 8x16B chunks
  const int sch8  = ((t & 7) ^ (srow8 & 7)) * 8;            // source-side inverse swizzle
  const unsigned short* gX0 = Xbf + (size_t)(b0 + srow8) * D_N + sch8;   // + k0
  const unsigned short* gM0 = Mbf + (size_t)srow8 * D_N + sch8;          // + sS*D_N + k0
  const int mrow = t >> 4;                                  // PV: 32 rows/issue, 16x16B chunks
  const int mch  = ((t & 15) ^ (mrow & 7)) * 8;
  const unsigned short* gT0 = Mt + (size_t)mrow * S_N + mch;             // + dc*128*S_N + sS

  #define ISSUE_QK(sS_, k0_, sl_) do {                                       \
    unsigned short* bA_ = &sbuf[(sl_)][0];                                   \
    unsigned short* bB_ = &sbuf[(sl_)][8192];                                \
    const unsigned short* gM_ = gM0 + (size_t)(sS_) * D_N + (k0_);           \
    stage16(gM_,                   bA_ + w * 512);                           \
    stage16(gM_ + (size_t)64*D_N,  bA_ + 4096 + w * 512);                    \
    const unsigned short* gX_ = gX0 + (k0_);                                 \
    stage16(gX_,                   bB_ + w * 512);                           \
    stage16(gX_ + (size_t)64*D_N,  bB_ + 4096 + w * 512);                    \
  } while (0)

  #define ISSUE_PV(sS_, dc_, sl_) do {                                       \
    unsigned short* bT_ = &sbuf[(sl_)][0];                                   \
    const unsigned short* gT_ = gT0 + (size_t)((dc_) * 128) * S_N + (sS_);   \
    stage16(gT_,                   bT_ + w * 512);                           \
    stage16(gT_ + (size_t)32*S_N,  bT_ + 4096 + w * 512);                    \
    stage16(gT_ + (size_t)64*S_N,  bT_ + 8192 + w * 512);                    \
    stage16(gT_ + (size_t)96*S_N,  bT_ + 12288 + w * 512);                   \
  } while (0)

  // prologue: phases 0 and 1 of sub 0 into slots 0, 1
  ISSUE_QK(s0, 0, 0);
  ISSUE_QK(s0, 64, 1);

  for (int sub = 0; sub < NSUB; ++sub) {
    const int sS = s0 + sub * SB;

    // ---------------- QK phases 0..7 (k0 = ph*64, slot ph%3) ----------------
    f32x4 accP[2][4];
    #pragma unroll
    for (int i = 0; i < 2; ++i)
      #pragma unroll
      for (int j = 0; j < 4; ++j) accP[i][j] = (f32x4){0.f, 0.f, 0.f, 0.f};

    #pragma unroll
    for (int ph = 0; ph < 8; ++ph) {
      asm volatile("s_waitcnt vmcnt(4)" ::: "memory");
      __builtin_amdgcn_s_barrier();
      if (ph < 6) { ISSUE_QK(sS, (ph + 2) * 64, (ph + 2) % 3); }
      else        { ISSUE_PV(sS, ph - 6, (ph + 2) % 3); }
      const unsigned short* As = &sbuf[ph % 3][0];
      const unsigned short* Bs = &sbuf[ph % 3][8192];
      __builtin_amdgcn_s_setprio(1);
      #pragma unroll
      for (int kk = 0; kk < 64; kk += 32) {
        const int cq = (kk >> 3) + quad;
        bf16x8 a[2], b[4];
        #pragma unroll
        for (int i = 0; i < 2; ++i)
          a[i] = *(const bf16x8*)&As[(qr * 32 + i * 16 + l15) * 64 + ((cq ^ x7) << 3)];
        #pragma unroll
        for (int j = 0; j < 4; ++j)
          b[j] = *(const bf16x8*)&Bs[(qc * 64 + j * 16 + l15) * 64 + ((cq ^ x7) << 3)];
        #pragma unroll
        for (int i = 0; i < 2; ++i)
          #pragma unroll
          for (int j = 0; j < 4; ++j)
            accP[i][j] = __builtin_amdgcn_mfma_f32_16x16x32_bf16(a[i], b[j], accP[i][j], 0, 0, 0);
      }
      __builtin_amdgcn_s_setprio(0);
    }

    // ------------- epilogue: p = exp2(dot * rx_b * rm_s), rowsum, P -> LDS -------------
    // C layout: s = qr*32 + i*16 + quad*4 + r (4 consecutive), b = qc*64 + j*16 + l15
    {
      const float4 rm0 = *(const float4*)&rminv[sS + qr * 32 + quad * 4];
      const float4 rm1 = *(const float4*)&rminv[sS + qr * 32 + 16 + quad * 4];
      #pragma unroll
      for (int i = 0; i < 2; ++i) {
        const float4 rm = i ? rm1 : rm0;
        const int sl = qr * 32 + i * 16 + quad * 4;   // local s base (mult of 4)
        #pragma unroll
        for (int j = 0; j < 4; ++j) {
          const float p0 = exp2f(accP[i][j][0] * rxj[j] * rm.x);
          const float p1 = exp2f(accP[i][j][1] * rxj[j] * rm.y);
          const float p2 = exp2f(accP[i][j][2] * rxj[j] * rm.z);
          const float p3 = exp2f(accP[i][j][3] * rxj[j] * rm.w);
          ls[j] += (p0 + p1) + (p2 + p3);
          const int brow = qc * 64 + j * 16 + l15;
          uint2 pk;
          pk.x = (unsigned)f2bf(p0) | ((unsigned)f2bf(p1) << 16);
          pk.y = (unsigned)f2bf(p2) | ((unsigned)f2bf(p3) << 16);
          *(uint2*)&Ps[brow * PSTRIDE + sl] = pk;       // padded row, no swizzle needed
        }
      }
      asm volatile("s_waitcnt lgkmcnt(0)" ::: "memory");  // Ps writes done before next barrier
    }

    // ---------------- PV phases 8..11 (dc = 0..3, slot (8+dc)%3) ----------------
    #pragma unroll
    for (int dc = 0; dc < 4; ++dc) {
      if (dc == 3 && sub == NSUB - 1) asm volatile("s_waitcnt vmcnt(0)" ::: "memory");
      else                            asm volatile("s_waitcnt vmcnt(4)" ::: "memory");
      __builtin_amdgcn_s_barrier();
      if (dc < 2)                { ISSUE_PV(sS, dc + 2, (10 + dc) % 3); }
      else if (sub < NSUB - 1)   { ISSUE_QK(sS + SB, (dc - 2) * 64, (10 + dc) % 3); }
      const unsigned short* Tsb = &sbuf[(8 + dc) % 3][0];
      __builtin_amdgcn_s_setprio(1);
      #pragma unroll
      for (int kk = 0; kk < 128; kk += 32) {
        const int cq = (kk >> 3) + quad;
        bf16x8 pa[2], mb[4];
        #pragma unroll
        for (int i = 0; i < 2; ++i)
          pa[i] = *(const bf16x8*)&Ps[(qr * 32 + i * 16 + l15) * PSTRIDE + (cq << 3)];
        #pragma unroll
        for (int j = 0; j < 4; ++j)
          mb[j] = *(const bf16x8*)&Tsb[(qc * 64 + j * 16 + l15) * 128 + ((cq ^ x7) << 3)];
        #pragma unroll
        for (int i = 0; i < 2; ++i)
          #pragma unroll
          for (int j = 0; j < 4; ++j)
            accO[dc][i][j] = __builtin_amdgcn_mfma_f32_16x16x32_bf16(pa[i], mb[j], accO[dc][i][j], 0, 0, 0);
      }
      __builtin_amdgcn_s_setprio(0);
    }
  }

  // ---------------- write O partials (coalesced over d via l15) ----------------
  float* Od = Opart + (size_t)chunk * ((size_t)B_N * D_N);
  #pragma unroll
  for (int dc = 0; dc < 4; ++dc)
    #pragma unroll
    for (int i = 0; i < 2; ++i)
      #pragma unroll
      for (int r = 0; r < 4; ++r) {
        const int bb = b0 + qr * 32 + i * 16 + quad * 4 + r;
        #pragma unroll
        for (int j = 0; j < 4; ++j) {
          const int d = dc * 128 + qc * 64 + j * 16 + l15;
          Od[(size_t)bb * D_N + d] = accO[dc][i][j][r];
        }
      }

  // ---------------- lsum: quad-reduce, cross-wave via LDS, one atomic per b ----------------
  __syncthreads();
  float* red = (float*)&sbuf[0][0];          // 8 waves x 64 b-slots
  #pragma unroll
  for (int j = 0; j < 4; ++j) {
    float v = ls[j];
    v += __shfl_xor(v, 16);
    v += __shfl_xor(v, 32);
    if (lane < 16) red[w * 64 + j * 16 + lane] = v;
  }
  __syncthreads();
  if (t < 128) {
    const int qc2 = t >> 6, idx = t & 63;
    float s = red[(0 + qc2) * 64 + idx] + red[(2 + qc2) * 64 + idx] +
              red[(4 + qc2) * 64 + idx] + red[(6 + qc2) * 64 + idx];
    unsafeAtomicAdd(&lsum[b0 + t], s);
  }
  #undef ISSUE_QK
  #undef ISSUE_PV
}

// ---------------- combine: out = (sum_ks Opart) / lsum ----------------
__global__ void k_combine(const float* __restrict__ Opart, const float* __restrict__ lsum,
                          float* __restrict__ out) {
  const int idx = blockIdx.x * 256 + threadIdx.x;  // float4 index, 131072 total
  const int b = idx >> 7;
  float4 s = {0.f, 0.f, 0.f, 0.f};
  #pragma unroll
  for (int ks = 0; ks < NS; ++ks) {
    float4 v = ((const float4*)Opart)[(size_t)ks * (B_N * D_N / 4) + idx];
    s.x += v.x; s.y += v.y; s.z += v.z; s.w += v.w;
  }
  const float inv = 1.0f / lsum[b];
  s.x *= inv; s.y *= inv; s.z *= inv; s.w *= inv;
  ((float4*)out)[idx] = s;
}

extern "C" void kernel_launch(void* const* d_in, const int* in_sizes, int n_in,
                              void* d_out, int out_size, void* d_ws, size_t ws_size,
                              hipStream_t stream) {
  const float* X = (const float*)d_in[0];
  const float* M = (const float*)d_in[1];
  char* ws = (char*)d_ws;
  unsigned short* Mbf = (unsigned short*)(ws + OFF_MBF);
  unsigned short* Mt  = (unsigned short*)(ws + OFF_MT);
  unsigned short* Xbf = (unsigned short*)(ws + OFF_XBF);
  float* rxv  = (float*)(ws + OFF_RX);
  float* rmv  = (float*)(ws + OFF_RM);
  float* lsum = (float*)(ws + OFF_LSUM);
  float* Opart = (float*)(ws + OFF_OPART);

  hipMemsetAsync(lsum, 0, B_N * sizeof(float), stream);
  k_prep_x<<<dim3(B_N), 128, 0, stream>>>(X, Xbf, rxv);
  k_cvt<<<dim3(S_N / 16), 256, 0, stream>>>(M, Mbf, rmv);
  k_tr<<<dim3((D_N / 128) * (S_N / 128)), 256, 0, stream>>>(Mbf, Mt);
  k_fused<<<dim3(8 * NS), 512, 0, stream>>>(Xbf, Mbf, Mt, rxv, rmv, lsum, Opart);
  k_combine<<<dim3(B_N * D_N / 4 / 256), 256, 0, stream>>>(Opart, lsum, (float*)d_out);
}